// Round 5
// baseline (99.743 us; speedup 1.0000x reference)
//
#include <hip/hip_runtime.h>

// ChamferLoss: x,y [4, 8192, 3] fp32 -> scalar fp32.
// out = (sum_bn min_m d2 + sum_bm min_n d2) / 32768
//
// Round 5: wave-uniform global loads are TCP-bound (R1-R3) and SMEM streaming
// stalls on lgkmcnt drains (R4: 61% VALUBusy, 2x issue overhead). Fix: stage
// each block's 1024 opposite records PACKED into LDS once (fuses the old prep
// kernel), then sweep via ds_read_b128 broadcast (same-address = free, DS pipe
// co-issues with VALU, immediate offsets only). Q=16 queries/lane halves
// record-visits vs R4: DS ~10us hidden under VALU ~14us floor.
// Math: v_pk_fma_f32 + op_sel cross-swap, 2-query x 2-point cell in
// 6 pk_fma + 2 v_min3 (verified bit-exact in R4).

#define N_      8192
#define NQ      65536         // total queries (2 sides)
#define FLT_BIG 3.0e38f

typedef float v2f __attribute__((ext_vector_type(2)));

__global__ void zero_out_kernel(float* out) { *out = 0.0f; }

// ---------------- init: pmin = +inf ----------------
__global__ __launch_bounds__(256) void init_kernel(unsigned int* __restrict__ pmin)
{
    int i = blockIdx.x * 256 + threadIdx.x;    // grid 64 -> 16384 uint4
    ((uint4*)pmin)[i] = make_uint4(0x7F800000u, 0x7F800000u, 0x7F800000u, 0x7F800000u);
}

// ---------------- main ----------------
// 256 blocks x 1024 thr (16 waves). Block = (dir, batch, qgroup of 1024
// queries, record-segment of 1024 records). All 16 waves hold the block's
// 1024 queries (16/lane); wave w sweeps records w*64..w*64+63 from LDS.

__global__ __launch_bounds__(1024, 4) void chamfer_kernel(
    const float* __restrict__ xraw, const float* __restrict__ yraw,
    unsigned int* __restrict__ pmin)
{
    // 64 KB union: phase A = 2048 float4 packed records (32 KB);
    // phase B = red[16][1024] floats (64 KB), after a barrier.
    __shared__ float4 lds4[4096];

    const int tid  = threadIdx.x;
    const int lane = tid & 63;
    const int wave = __builtin_amdgcn_readfirstlane(tid >> 6);
    const int blk  = blockIdx.x;               // 0..255
    const int dir   = blk >> 7;                // 0: x-queries vs y, 1: y vs x
    const int batch = (blk >> 5) & 3;
    const int qg    = (blk >> 2) & 7;          // query group (1024 q)
    const int seg   = blk & 3;                 // record segment (1024 recs)

    const float* qraw = dir ? yraw : xraw;
    const float* oraw = dir ? xraw : yraw;

    // ---- stage: pack this block's 1024 records {x0,x1,y0,y1}{z0,z1,w0,w1} ----
    {
        int r = tid;                           // one record (2 points) per thread
        const float2* p2 = (const float2*)(oraw + ((size_t)batch * N_ + seg * 2048 + 2 * r) * 3);
        float2 a = p2[0], b = p2[1], c = p2[2];   // x0,y0 | z0,x1 | y1,z1
        float w0 = fmaf(a.x, a.x, fmaf(a.y, a.y, b.x * b.x));
        float w1 = fmaf(b.y, b.y, fmaf(c.x, c.x, c.y * c.y));
        lds4[2*r]   = make_float4(a.x, b.y, a.y, c.x);
        lds4[2*r+1] = make_float4(b.x, c.y, w0, w1);
    }

    // ---- load this lane's 16 queries (48 contiguous floats, 16B aligned) ----
    const int qbase = batch * N_ + qg * 1024;
    v2f qx[8], qy[8], qz[8];
    float acc[16];
    {
        float f[48];
        const float4* qv = (const float4*)(qraw + (size_t)qbase * 3) + lane * 12;
        #pragma unroll
        for (int k = 0; k < 12; ++k) {
            float4 t = qv[k];
            f[4*k] = t.x; f[4*k+1] = t.y; f[4*k+2] = t.z; f[4*k+3] = t.w;
        }
        #pragma unroll
        for (int j = 0; j < 8; ++j) {
            qx[j] = (v2f){-2.0f * f[6*j+0], -2.0f * f[6*j+3]};
            qy[j] = (v2f){-2.0f * f[6*j+1], -2.0f * f[6*j+4]};
            qz[j] = (v2f){-2.0f * f[6*j+2], -2.0f * f[6*j+5]};
            acc[2*j] = FLT_BIG; acc[2*j+1] = FLT_BIG;
        }
    }
    __syncthreads();

    // ---- sweep: 64 records from LDS, broadcast reads, immediate offsets ----
    const float4* rp = lds4 + wave * 128;      // wave's 64 records
    #pragma unroll 8
    for (int k = 0; k < 64; ++k) {
        float4 u = rp[2*k];                    // {x0,x1,y0,y1}
        float4 v = rp[2*k+1];                  // {z0,z1,w0,w1}
        v2f px = (v2f){u.x, u.y};
        v2f py = (v2f){u.z, u.w};
        v2f pz = (v2f){v.x, v.y};
        v2f w2 = (v2f){v.z, v.w};
        #pragma unroll
        for (int j = 0; j < 8; ++j) {
            v2f td, ts;
            // td = {q0p0+w0, q1p1+w1}; ts = {q0p1+w1, q1p0+w0} via op_sel swap
            asm("v_pk_fma_f32 %0, %1, %2, %3"
                : "=v"(td) : "v"(qz[j]), "v"(pz), "v"(w2));
            asm("v_pk_fma_f32 %0, %1, %2, %3 op_sel:[0,1,1] op_sel_hi:[1,0,0]"
                : "=v"(ts) : "v"(qz[j]), "v"(pz), "v"(w2));
            asm("v_pk_fma_f32 %0, %1, %2, %0"
                : "+v"(td) : "v"(qy[j]), "v"(py));
            asm("v_pk_fma_f32 %0, %1, %2, %0 op_sel:[0,1,0] op_sel_hi:[1,0,1]"
                : "+v"(ts) : "v"(qy[j]), "v"(py));
            asm("v_pk_fma_f32 %0, %1, %2, %0"
                : "+v"(td) : "v"(qx[j]), "v"(px));
            asm("v_pk_fma_f32 %0, %1, %2, %0 op_sel:[0,1,0] op_sel_hi:[1,0,1]"
                : "+v"(ts) : "v"(qx[j]), "v"(px));
            asm("v_min3_f32 %0, %0, %1, %2" : "+v"(acc[2*j])   : "v"(td.x), "v"(ts.x));
            asm("v_min3_f32 %0, %0, %1, %2" : "+v"(acc[2*j+1]) : "v"(td.y), "v"(ts.y));
        }
    }
    __syncthreads();                           // all waves done reading records

    // ---- combine 16 wave-partials per query ----
    float* red = (float*)lds4;                 // red[w*1024 + qlocal]
    {
        float4* rw = (float4*)&red[wave * 1024 + lane * 16];
        rw[0] = make_float4(acc[0],  acc[1],  acc[2],  acc[3]);
        rw[1] = make_float4(acc[4],  acc[5],  acc[6],  acc[7]);
        rw[2] = make_float4(acc[8],  acc[9],  acc[10], acc[11]);
        rw[3] = make_float4(acc[12], acc[13], acc[14], acc[15]);
    }
    __syncthreads();

    // thread t owns block-query t
    float m = red[tid];
    #pragma unroll
    for (int w = 1; w < 16; ++w) m = fminf(m, red[w * 1024 + tid]);
    int gq = qbase + tid;
    float ax = qraw[gq*3+0], ay = qraw[gq*3+1], az = qraw[gq*3+2];
    float qn = fmaf(ax, ax, fmaf(ay, ay, az * az));
    float d2 = fmaxf(0.0f, qn + m);            // relu commutes with min
    atomicMin(&pmin[dir * 32768 + gq], __float_as_uint(d2));
}

// ---------------- sum: single block, deterministic, writes out directly ----
__global__ __launch_bounds__(1024) void sum_kernel(
    const unsigned int* __restrict__ pmin, float* __restrict__ out)
{
    __shared__ float sred[16];
    const int tid = threadIdx.x;
    const float4* pv = (const float4*)pmin;    // bits are valid non-neg floats
    float s = 0.0f;
    #pragma unroll
    for (int k = 0; k < 16; ++k) {             // 16384 float4 / 1024 threads
        float4 v = pv[k * 1024 + tid];
        s += v.x + v.y + v.z + v.w;
    }
    #pragma unroll
    for (int off = 32; off > 0; off >>= 1) s += __shfl_xor(s, off);
    if ((tid & 63) == 0) sred[tid >> 6] = s;
    __syncthreads();
    if (tid < 16) {
        float v = sred[tid];
        #pragma unroll
        for (int off = 8; off > 0; off >>= 1) v += __shfl_xor(v, off);
        if (tid == 0) *out = v * (1.0f / 32768.0f);
    }
}

// ---------------- fallback (ws too small): round-1 kernel ----------------
__global__ __launch_bounds__(1024) void chamfer_raw_kernel(
    const float* __restrict__ xraw, const float* __restrict__ yraw,
    float* __restrict__ out)
{
    __shared__ float4 red4[16][64];
    const int tid  = threadIdx.x;
    const int wave = tid >> 6;
    const int lane = tid & 63;
    const int blk  = blockIdx.x;
    const bool xdir = (blk < 128);
    const int b    = (blk & 127) >> 5;
    const int qofs = (blk & 31) << 8;
    const float* qraw = xdir ? xraw : yraw;
    const float* oraw = xdir ? yraw : xraw;
    float qx0[4], qx1[4], qx2[4], acc[4];
    #pragma unroll
    for (int q = 0; q < 4; ++q) {
        int gq = b * N_ + qofs + lane*4 + q;
        qx0[q] = qraw[gq*3+0]; qx1[q] = qraw[gq*3+1]; qx2[q] = qraw[gq*3+2];
        acc[q] = FLT_BIG;
    }
    const float* opp = oraw + (size_t)(b * N_ + wave * 512) * 3;
    #pragma unroll 4
    for (int k = 0; k < 512; ++k) {
        float p0 = opp[k*3+0], p1 = opp[k*3+1], p2 = opp[k*3+2];
        float w  = fmaf(p0, p0, fmaf(p1, p1, p2*p2));
        #pragma unroll
        for (int q = 0; q < 4; ++q) {
            float dot = qx0[q]*p0 + qx1[q]*p1 + qx2[q]*p2;
            acc[q] = fminf(acc[q], fmaf(-2.0f, dot, w));
        }
    }
    red4[wave][lane] = make_float4(acc[0], acc[1], acc[2], acc[3]);
    __syncthreads();
    if (tid < 256) {
        const float* red = (const float*)red4;
        float m = red[tid];
        #pragma unroll
        for (int w = 1; w < 16; ++w) m = fminf(m, red[w*256 + tid]);
        int gq = b * N_ + qofs + tid;
        float ax = qraw[gq*3+0], ay = qraw[gq*3+1], az = qraw[gq*3+2];
        float d2 = fmaxf(0.0f, fmaf(ax,ax,fmaf(ay,ay,az*az)) + m);
        #pragma unroll
        for (int off = 32; off > 0; off >>= 1) d2 += __shfl_xor(d2, off);
        if ((tid & 63) == 0) atomicAdd(out, d2 * (1.0f / 32768.0f));
    }
}

extern "C" void kernel_launch(void* const* d_in, const int* in_sizes, int n_in,
                              void* d_out, int out_size, void* d_ws, size_t ws_size,
                              hipStream_t stream)
{
    const float* x = (const float*)d_in[0];
    const float* y = (const float*)d_in[1];
    float* out = (float*)d_out;

    const size_t need = (size_t)NQ * 4;        // 256 KB pmin
    if (ws_size >= need) {
        unsigned int* pmin = (unsigned int*)d_ws;
        init_kernel<<<64, 256, 0, stream>>>(pmin);
        chamfer_kernel<<<256, 1024, 0, stream>>>(x, y, pmin);
        sum_kernel<<<1, 1024, 0, stream>>>(pmin, out);
    } else {
        zero_out_kernel<<<1, 1, 0, stream>>>(out);
        chamfer_raw_kernel<<<256, 1024, 0, stream>>>(x, y, out);
    }
}